// Round 11
// baseline (341.467 us; speedup 1.0000x reference)
//
#include <hip/hip_runtime.h>
#include <hip/hip_bf16.h>
#include <stdint.h>

#define DIM 512
#define NROWS 1024
#define NCLS 100000
#define NST 391                         // stripes of 256 cols
#define NCLS_PAD (NST * 256)            // 100096
#define SCALE_S 64.0f
#define NBN 64                          // stripe-columns covered by the grid
#define S_LOG2E 92.332482616893662f     // 64 * log2(e)

typedef __attribute__((ext_vector_type(8))) __bf16 bf16x8;
typedef __attribute__((ext_vector_type(4))) float f32x4;

__device__ __forceinline__ unsigned short f2bf(float x) {
  __hip_bfloat16 h = __float2bfloat16(x);
  union { __hip_bfloat16 h; unsigned short u; } v; v.h = h; return v.u;
}
__device__ __forceinline__ unsigned pack2(float a, float b) {
  return ((unsigned)f2bf(b) << 16) | (unsigned)f2bf(a);
}
__device__ __forceinline__ void async_ld16(const void* g, void* l) {
  __builtin_amdgcn_global_load_lds((const __attribute__((address_space(1))) void*)g,
                                   (__attribute__((address_space(3))) void*)l, 16, 0, 0);
}

// ---------------- kernel 1a: normalize inputs -> bf16 ----------------
__global__ void prep_a(const float* __restrict__ X, unsigned short* __restrict__ A16,
                       float* __restrict__ xnorm) {
  const int row = blockIdx.x;
  const int lane = threadIdx.x;  // 64
  const float4* xp = (const float4*)(X + (size_t)row * DIM);
  float4 v0 = xp[lane];
  float4 v1 = xp[lane + 64];
  float ss = v0.x*v0.x + v0.y*v0.y + v0.z*v0.z + v0.w*v0.w
           + v1.x*v1.x + v1.y*v1.y + v1.z*v1.z + v1.w*v1.w;
  #pragma unroll
  for (int m = 1; m < 64; m <<= 1) ss += __shfl_xor(ss, m);
  const float nrm = sqrtf(ss);
  const float inv = 1.0f / fmaxf(nrm, 1e-12f);
  if (lane == 0) xnorm[row] = nrm;
  unsigned short* ap = A16 + (size_t)row * DIM;
  *(uint2*)(ap + lane * 4)       = make_uint2(pack2(v0.x*inv, v0.y*inv), pack2(v0.z*inv, v0.w*inv));
  *(uint2*)(ap + 256 + lane * 4) = make_uint2(pack2(v1.x*inv, v1.y*inv), pack2(v1.z*inv, v1.w*inv));
}

// ---------------- kernel 1b: normalize weight rows -> bf16 (padded to 100096) ----------------
__global__ void prep_w(const float* __restrict__ Wg, unsigned short* __restrict__ W16) {
  const int row = blockIdx.x * 4 + (threadIdx.x >> 6);
  const int lane = threadIdx.x & 63;
  unsigned short* op = W16 + (size_t)row * DIM;
  if (row >= NCLS) {                       // zero-pad tail rows (cos=0 -> exp(-64)~0)
    *(uint4*)((char*)op + lane * 16) = make_uint4(0, 0, 0, 0);
    return;
  }
  const float4* xp = (const float4*)(Wg + (size_t)row * DIM);
  float4 v0 = xp[lane];
  float4 v1 = xp[lane + 64];
  float ss = v0.x*v0.x + v0.y*v0.y + v0.z*v0.z + v0.w*v0.w
           + v1.x*v1.x + v1.y*v1.y + v1.z*v1.z + v1.w*v1.w;
  #pragma unroll
  for (int m = 1; m < 64; m <<= 1) ss += __shfl_xor(ss, m);
  const float inv = 1.0f / fmaxf(sqrtf(ss), 1e-12f);
  *(uint2*)(op + lane * 4)       = make_uint2(pack2(v0.x*inv, v0.y*inv), pack2(v0.z*inv, v0.w*inv));
  *(uint2*)(op + 256 + lane * 4) = make_uint2(pack2(v1.x*inv, v1.y*inv), pack2(v1.z*inv, v1.w*inv));
}

// ---------------- kernel 2: 256-tile GEMM + fixed-max sumexp partials ----------------
// 512 threads (8 waves = 2M x 4N), block tile BM=256 x stripe 256, BK=64.
// acc[8][4] (128 regs) anchored in AGPRs; hard budget is 256 regs/wave
// (8 co-resident waves = 2/SIMD), so arch working set must stay <= 128.
// Rounds 8-10 spilled because the 8-phase stripe body was fully unrolled
// (scheduler hoisting blew peak pressure). This round: FLAT RUNTIME TILE LOOP,
// manual 2-step ping-pong (compile-time LDS slot), per-iteration working set
// ~80 arch regs -> no spill. Counted s_waitcnt vmcnt(8), never 0 mid-loop.

__device__ __forceinline__ void stage_tile(const char* Ab, const char* W16g,
                                           long col0, int kt, int slot,
                                           int wave, int lane, char* lds) {
  char* dstA = lds + slot * 65536;
  char* dstB = dstA + 32768;
  const char* Wb = W16g + (size_t)col0 * 1024;
  #pragma unroll
  for (int it = 0; it < 4; ++it) {
    const int chunk = wave * 4 + it;               // 32 chunks x 1KB each
    const int d = chunk * 1024 + lane * 16;        // linear LDS byte this lane fills
    const int row = d >> 7;                        // tile row/col (128B per row)
    const int b = d & 127;
    const int srel = row * 1024 + kt * 128 + (b ^ ((row & 7) << 4)); // pre-swizzled src
    async_ld16(Ab + srel, dstA + chunk * 1024);    // dest: wave-uniform base
    async_ld16(Wb + srel, dstB + chunk * 1024);
  }
}

__device__ __forceinline__ void compute_tile(const char* lds, int slot, int wr, int wn,
                                             int lr, int lg, f32x4 (&acc)[8][4]) {
  const char* Ab = lds + slot * 65536;
  const char* Bb = Ab + 32768;
  #pragma unroll
  for (int kh = 0; kh < 2; ++kh) {
    bf16x8 afr[8]; bf16x8 bfr[4];
    #pragma unroll
    for (int mi = 0; mi < 8; ++mi) {
      const int row = wr * 128 + mi * 16 + lr;
      afr[mi] = *(const bf16x8*)(Ab + row * 128 + ((kh * 64 + lg * 16) ^ ((row & 7) << 4)));
    }
    #pragma unroll
    for (int ni = 0; ni < 4; ++ni) {
      const int col = wn * 64 + ni * 16 + lr;
      bfr[ni] = *(const bf16x8*)(Bb + col * 128 + ((kh * 64 + lg * 16) ^ ((col & 7) << 4)));
    }
    #pragma unroll
    for (int mi = 0; mi < 8; ++mi)
      #pragma unroll
      for (int ni = 0; ni < 4; ++ni)
        acc[mi][ni] = __builtin_amdgcn_mfma_f32_16x16x32_bf16(afr[mi], bfr[ni], acc[mi][ni], 0, 0, 0);
  }
  // Anchor the accumulator in AGPRs (no-op when already resident).
  #pragma unroll
  for (int mi = 0; mi < 8; ++mi)
    #pragma unroll
    for (int ni = 0; ni < 4; ++ni)
      asm volatile("" : "+a"(acc[mi][ni]));
}

// One pipeline step for compile-time SLOT: compute tile i (SLOT), stage tile
// i+1 (SLOT^1). Per-stripe epilogue on (i&7)==7 (uniform branch).
#define STEP(SLOT)                                                                 \
  do {                                                                             \
    const int j = i + 1;                                                           \
    __builtin_amdgcn_s_barrier();        /* compute of slot SLOT^1 done */         \
    if (j < ntiles) {                                                              \
      const int ktj = j & 7;                                                       \
      if (ktj == 0) stageCol += (long)NBN * 256;                                   \
      stage_tile(Ab, W16g, stageCol, ktj, (SLOT) ^ 1, wave, lane, lds);            \
      asm volatile("s_waitcnt vmcnt(8)" ::: "memory");                             \
    } else {                                                                       \
      asm volatile("s_waitcnt vmcnt(0)" ::: "memory");                             \
    }                                                                              \
    __builtin_amdgcn_s_barrier();        /* tile i (slot SLOT) staged */           \
    compute_tile(lds, (SLOT), wr, wn, lr, lg, acc);                                \
    if ((i & 7) == 7) {                                                            \
      _Pragma("unroll")                                                            \
      for (int mi = 0; mi < 8; ++mi)                                               \
        _Pragma("unroll")                                                          \
        for (int ni = 0; ni < 4; ++ni)                                             \
          _Pragma("unroll")                                                        \
          for (int r = 0; r < 4; ++r) {                                            \
            float c = fminf(1.f, fmaxf(-1.f, acc[mi][ni][r]));   /* med3 */        \
            srow[mi][r] += exp2f(fmaf(c, S_LOG2E, -S_LOG2E));                      \
            acc[mi][ni][r] = 0.f;                                                  \
          }                                                                        \
    }                                                                              \
    ++i;                                                                           \
  } while (0)

__global__ __launch_bounds__(512, 1) void gemm_lse3(
    const unsigned short* __restrict__ A16, const unsigned short* __restrict__ W16,
    float* __restrict__ part_s) {
  __shared__ char lds[2 * 65536];          // 128 KB: 2 x (A 32KB + B 32KB)
  const char* W16g = (const char*)W16;

  const int tid = threadIdx.x;
  const int lane = tid & 63;
  const int wave = tid >> 6;               // 0..7
  const int lr = lane & 15, lg = lane >> 4;
  const int wr = wave >> 2;                // M half: 0..1
  const int wn = wave & 3;                 // N quarter: 0..3

  // bid -> (mblk, nblk): 4 mblks of one stripe-column land on one XCD (bid&7)
  const int bid = blockIdx.x;              // 256 blocks
  const int x = bid & 7;
  const int q = bid >> 3;                  // 0..31
  const int mblk = q & 3;                  // 0..3
  const int nblk = x * 8 + (q >> 2);       // 0..63
  const int mrow0 = mblk * 256;

  const char* Ab = (const char*)A16 + (size_t)mrow0 * 1024;

  f32x4 acc[8][4];
  #pragma unroll
  for (int mi = 0; mi < 8; ++mi)
    #pragma unroll
    for (int ni = 0; ni < 4; ++ni) acc[mi][ni] = f32x4{0.f, 0.f, 0.f, 0.f};
  float srow[8][4];
  #pragma unroll
  for (int mi = 0; mi < 8; ++mi)
    #pragma unroll
    for (int r = 0; r < 4; ++r) srow[mi][r] = 0.f;

  const int nstr = (NST - nblk + NBN - 1) / NBN;   // 6 or 7 stripes for this block
  const int ntiles = nstr * 8;                     // flat (stripe x K-tile) count
  long stageCol = (long)nblk * 256;                // col0 of stripe being staged

  stage_tile(Ab, W16g, stageCol, 0, 0, wave, lane, lds);   // prologue: tile 0 -> slot 0

  int i = 0;
  while (i < ntiles) {                     // ntiles is even: 2 steps per pass
    STEP(0);
    STEP(1);
  }

  // ---- reduce: lr-lanes (16 cols) in-wave, then 4 wn-waves via LDS ----
  float* ldsrow = (float*)lds;             // 4 wn x 256 rows (pipeline done, LDS free)
  __builtin_amdgcn_s_barrier();
  #pragma unroll
  for (int mi = 0; mi < 8; ++mi)
    #pragma unroll
    for (int r = 0; r < 4; ++r) {
      float v = srow[mi][r];
      v += __shfl_xor(v, 1); v += __shfl_xor(v, 2);
      v += __shfl_xor(v, 4); v += __shfl_xor(v, 8);
      if (lr == 0)
        ldsrow[wn * 256 + wr * 128 + mi * 16 + lg * 4 + r] = v;
    }
  __builtin_amdgcn_s_barrier();
  asm volatile("s_waitcnt lgkmcnt(0)" ::: "memory");
  if (tid < 256) {
    float v = ldsrow[tid] + ldsrow[256 + tid] + ldsrow[512 + tid] + ldsrow[768 + tid];
    part_s[(size_t)nblk * NROWS + mrow0 + tid] = v;
  }
}

// ---------------- kernel 3: precise f32 target logit + merge partials ----------------
__global__ void finalize_kernel(const float* __restrict__ X, const int* __restrict__ labels,
                                const float* __restrict__ Wg, const float* __restrict__ xnorm,
                                const float* __restrict__ part_s, float* __restrict__ rowloss) {
  const int row = blockIdx.x;
  const int lane = threadIdx.x;   // 64
  const int lbl = labels[row];
  const float4* xp = (const float4*)(X + (size_t)row * DIM);
  const float4* wp = (const float4*)(Wg + (size_t)lbl * DIM);
  float dot = 0.f, wss = 0.f;
  #pragma unroll
  for (int i = 0; i < 2; ++i) {
    float4 xv = xp[lane + 64 * i];
    float4 wv = wp[lane + 64 * i];
    dot += xv.x*wv.x + xv.y*wv.y + xv.z*wv.z + xv.w*wv.w;
    wss += wv.x*wv.x + wv.y*wv.y + wv.z*wv.z + wv.w*wv.w;
  }
  float psum = part_s[(size_t)lane * NROWS + row];   // 64 partials per row
  #pragma unroll
  for (int m = 1; m < 64; m <<= 1) {
    dot += __shfl_xor(dot, m); wss += __shfl_xor(wss, m); psum += __shfl_xor(psum, m);
  }
  if (lane == 0) {
    float c = dot / (fmaxf(xnorm[row], 1e-12f) * fmaxf(sqrtf(wss), 1e-12f));
    c = fminf(1.f, fmaxf(-1.f, c));
    const float cm = 0.99500416527802576610f;   // cos(0.1)
    const float sn = 0.09983341664682815230f;   // sin(0.1)
    float unmod = SCALE_S * c;                  // term the GEMM summed at the label column
    float modv  = SCALE_S * (c * cm - sqrtf(fmaxf(0.f, 1.f - c * c)) * sn); // S*cos(theta+m)
    float stot = psum - __expf(unmod - SCALE_S) + __expf(modv - SCALE_S);
    stot = fmaxf(stot, 1e-37f);
    rowloss[row] = (logf(stot) + SCALE_S) - modv;   // logsumexp - target logit
  }
}

// ---------------- kernel 4: mean over rows ----------------
__global__ void reduce_kernel(const float* __restrict__ rowloss, float* __restrict__ out) {
  const int tid = threadIdx.x;   // 256
  float s = 0.f;
  #pragma unroll
  for (int i = 0; i < 4; ++i) s += rowloss[tid + i * 256];
  #pragma unroll
  for (int m = 1; m < 64; m <<= 1) s += __shfl_xor(s, m);
  __shared__ float wsum[4];
  if ((tid & 63) == 0) wsum[tid >> 6] = s;
  __syncthreads();
  if (tid == 0) out[0] = (wsum[0] + wsum[1] + wsum[2] + wsum[3]) * (1.0f / NROWS);
}

extern "C" void kernel_launch(void* const* d_in, const int* in_sizes, int n_in,
                              void* d_out, int out_size, void* d_ws, size_t ws_size,
                              hipStream_t stream) {
  const float* X      = (const float*)d_in[0];
  const int*   labels = (const int*)d_in[1];
  const float* Wg     = (const float*)d_in[2];
  float* out = (float*)d_out;
  char* ws = (char*)d_ws;
  // ws layout (bytes):
  //   A16    @ 0            1,048,576
  //   W16    @ 1,048,576  102,498,304   (100096 x 512 x 2B, rows >= NCLS zeroed)
  //   part_s @ 103,546,880    262,144   (64 x 1024 x 4B)
  //   xnorm  @ 103,809,024      4,096
  //   rowloss@ 103,813,120      4,096
  unsigned short* A16 = (unsigned short*)ws;
  unsigned short* W16 = (unsigned short*)(ws + 1048576);
  float* part_s  = (float*)(ws + 103546880);
  float* xnorm   = (float*)(ws + 103809024);
  float* rowloss = (float*)(ws + 103813120);

  prep_a<<<NROWS, 64, 0, stream>>>(X, A16, xnorm);
  prep_w<<<NCLS_PAD / 4, 256, 0, stream>>>(Wg, W16);
  gemm_lse3<<<256, 512, 0, stream>>>(A16, W16, part_s);
  finalize_kernel<<<NROWS, 64, 0, stream>>>(X, labels, Wg, xnorm, part_s, rowloss);
  reduce_kernel<<<1, 256, 0, stream>>>(rowloss, out);
}

// Round 12
// 264.227 us; speedup vs baseline: 1.2923x; 1.2923x over previous
//
#include <hip/hip_runtime.h>
#include <hip/hip_bf16.h>
#include <stdint.h>

#define DIM 512
#define NROWS 1024
#define NCLS 100000
#define NCLS_PAD 100032
#define SCALE_S 64.0f
#define NBN 192                          // stripe columns of the grid (multiple of 8)
#define NST ((NCLS + 63) / 64)           // 1563 stripes of 64 cols
#define S_LOG2E 92.332482616893662f      // 64 * log2(e)

typedef __attribute__((ext_vector_type(8))) __bf16 bf16x8;
typedef __attribute__((ext_vector_type(4))) float f32x4;

__device__ __forceinline__ unsigned short f2bf(float x) {
  __hip_bfloat16 h = __float2bfloat16(x);
  union { __hip_bfloat16 h; unsigned short u; } v; v.h = h; return v.u;
}
__device__ __forceinline__ unsigned pack2(float a, float b) {
  return ((unsigned)f2bf(b) << 16) | (unsigned)f2bf(a);
}
__device__ __forceinline__ void async_ld16(const void* g, void* l) {
  __builtin_amdgcn_global_load_lds((const __attribute__((address_space(1))) void*)g,
                                   (__attribute__((address_space(3))) void*)l, 16, 0, 0);
}

// ---------------- kernel 1a: normalize inputs -> bf16 ----------------
__global__ void prep_a(const float* __restrict__ X, unsigned short* __restrict__ A16,
                       float* __restrict__ xnorm) {
  const int row = blockIdx.x;
  const int lane = threadIdx.x;  // 64
  const float4* xp = (const float4*)(X + (size_t)row * DIM);
  float4 v0 = xp[lane];
  float4 v1 = xp[lane + 64];
  float ss = v0.x*v0.x + v0.y*v0.y + v0.z*v0.z + v0.w*v0.w
           + v1.x*v1.x + v1.y*v1.y + v1.z*v1.z + v1.w*v1.w;
  #pragma unroll
  for (int m = 1; m < 64; m <<= 1) ss += __shfl_xor(ss, m);
  const float nrm = sqrtf(ss);
  const float inv = 1.0f / fmaxf(nrm, 1e-12f);
  if (lane == 0) xnorm[row] = nrm;
  unsigned short* ap = A16 + (size_t)row * DIM;
  *(uint2*)(ap + lane * 4)       = make_uint2(pack2(v0.x*inv, v0.y*inv), pack2(v0.z*inv, v0.w*inv));
  *(uint2*)(ap + 256 + lane * 4) = make_uint2(pack2(v1.x*inv, v1.y*inv), pack2(v1.z*inv, v1.w*inv));
}

// ---------------- kernel 1b: normalize weight rows -> bf16 (padded to 100032) ----------------
__global__ void prep_w(const float* __restrict__ Wg, unsigned short* __restrict__ W16) {
  const int row = blockIdx.x * 4 + (threadIdx.x >> 6);
  const int lane = threadIdx.x & 63;
  unsigned short* op = W16 + (size_t)row * DIM;
  if (row >= NCLS) {                       // zero-pad tail rows (cos=0 -> exp2(-92)~0)
    *(uint4*)((char*)op + lane * 16) = make_uint4(0, 0, 0, 0);
    return;
  }
  const float4* xp = (const float4*)(Wg + (size_t)row * DIM);
  float4 v0 = xp[lane];
  float4 v1 = xp[lane + 64];
  float ss = v0.x*v0.x + v0.y*v0.y + v0.z*v0.z + v0.w*v0.w
           + v1.x*v1.x + v1.y*v1.y + v1.z*v1.z + v1.w*v1.w;
  #pragma unroll
  for (int m = 1; m < 64; m <<= 1) ss += __shfl_xor(ss, m);
  const float inv = 1.0f / fmaxf(sqrtf(ss), 1e-12f);
  *(uint2*)(op + lane * 4)       = make_uint2(pack2(v0.x*inv, v0.y*inv), pack2(v0.z*inv, v0.w*inv));
  *(uint2*)(op + 256 + lane * 4) = make_uint2(pack2(v1.x*inv, v1.y*inv), pack2(v1.z*inv, v1.w*inv));
}

// ---------------- kernel 2: r2 structure + FIFO-ordered A double-buffer ----------------
// 256 threads (4 waves x 32 rows), BM=128, BN=64 stripe, BK=64 phases.
// W: 8-buffer LDS ring via global_load_lds, staged 6 phases ahead (r2, proven).
// A: per-phase 4xb128 from global (L2-resident, 1MB), DOUBLE-BUFFERED in regs:
//    phase q loads A(q+1) BEFORE issuing W-stage(q). FIFO: ops newer than A(q)
//    at phase q's MFMAs = Wstage(q-1) 2 + A(q+1) 4 + Wstage(q) 2 = 8, so the
//    steady s_waitcnt vmcnt(8) proves A(q) and W(q) done WITHOUT draining the
//    6-tile W prefetch queue (r2's diagnosed drain is structurally removed).
// Register census: afdb 32 + bfr 32 + acc 32 + srow 8 + addr ~20 = ~124 <= 128.

__device__ __forceinline__ void stage_w(const char* W16g, char* wldsb, int buf, int ktp,
                                        long tcol0, int wave, int lane) {
  #pragma unroll
  for (int it = 0; it < 2; ++it) {
    const int d = (wave * 2 + it) * 1024 + lane * 16;   // linear dest byte in 8KB tile
    const int c = d >> 7;                                // col within stripe (128B per col)
    const int b = d & 127;
    async_ld16(W16g + ((size_t)(tcol0 + c) * 1024 + ktp * 128 + (b ^ ((c & 7) << 4))),
               wldsb + buf * 8192 + (wave * 2 + it) * 1024);
  }
}

__device__ __forceinline__ void lda(bf16x8 (&dst)[2][2], const char* Ab, int kt,
                                    int lr, int lg) {
  #pragma unroll
  for (int kh = 0; kh < 2; ++kh)
    #pragma unroll
    for (int mi = 0; mi < 2; ++mi)
      dst[kh][mi] = *(const bf16x8*)(Ab + (size_t)(mi * 16 + lr) * 1024
                                        + kt * 128 + kh * 64 + lg * 16);
}

template<int KT>
__device__ __forceinline__ void mfma_phase(const char* wldsb, const bf16x8 (&afc)[2][2],
                                           f32x4 (&acc)[2][4], int lr, int lg) {
  const char* wb = wldsb + KT * 8192;
  bf16x8 bfr[2][4];
  #pragma unroll
  for (int kh = 0; kh < 2; ++kh)
    #pragma unroll
    for (int ni = 0; ni < 4; ++ni) {
      const int bc = ni * 16 + lr;
      const int o = (bc * 128 + kh * 64 + lg * 16) ^ ((bc & 7) << 4);
      bfr[kh][ni] = *(const bf16x8*)(wb + o);
    }
  #pragma unroll
  for (int kh = 0; kh < 2; ++kh)
    #pragma unroll
    for (int mi = 0; mi < 2; ++mi)
      #pragma unroll
      for (int ni = 0; ni < 4; ++ni)
        acc[mi][ni] = __builtin_amdgcn_mfma_f32_16x16x32_bf16(afc[kh][mi], bfr[kh][ni], acc[mi][ni], 0, 0, 0);
}

// Phase KT: prefetch A((KT+1)&7) into parity buffer, stage W 6 ahead, counted
// vmcnt, barrier, MFMA on af[KT&1] + W-ring[KT&7]. VMT used only when not staging.
#define PHASE(KT, VMT)                                                              \
  do {                                                                              \
    lda(af[((KT) + 1) & 1], Ab, ((KT) + 1) & 7, lr, lg);                            \
    if ((KT) < 2) {                                                                 \
      stage_w(W16g, wldsb, ((KT) + 6) & 7, (KT) + 6, col0, wave, lane);             \
      asm volatile("s_waitcnt vmcnt(8)" ::: "memory");                              \
    } else if (has_next) {                                                          \
      stage_w(W16g, wldsb, ((KT) + 6) & 7, (KT) - 2, ncol0, wave, lane);            \
      asm volatile("s_waitcnt vmcnt(8)" ::: "memory");                              \
    } else {                                                                        \
      asm volatile("s_waitcnt vmcnt(" #VMT ")" ::: "memory");                       \
    }                                                                               \
    __builtin_amdgcn_s_barrier();                                                   \
    mfma_phase<(KT)>(wldsb, af[(KT) & 1], acc, lr, lg);                             \
  } while (0)

__global__ __launch_bounds__(256, 2) void gemm_lse4(
    const unsigned short* __restrict__ A16, const unsigned short* __restrict__ W16,
    float* __restrict__ part_s) {
  __shared__ char wlds[8 * 8192];          // 64 KB ring of 8 x 8KB W tiles
  char* wldsb = wlds;
  const char* W16g = (const char*)W16;

  const int tid = threadIdx.x;
  const int lane = tid & 63;
  const int wave = tid >> 6;
  const int lr = lane & 15, lg = lane >> 4;
  // bid = 64g + 8m + x : all 8 M-blocks of stripe-column (8g+x) share XCD x
  const int bid = blockIdx.x;
  const int mblk = (bid >> 3) & 7;
  const int nblk = ((bid >> 6) << 3) + (bid & 7);   // 0..191

  const char* Ab = (const char*)A16 + (size_t)(mblk * 128 + wave * 32) * 1024;

  f32x4 acc[2][4];
  #pragma unroll
  for (int mi = 0; mi < 2; ++mi)
    #pragma unroll
    for (int ni = 0; ni < 4; ++ni) acc[mi][ni] = f32x4{0.f, 0.f, 0.f, 0.f};
  float srow[2][4];
  #pragma unroll
  for (int mi = 0; mi < 2; ++mi)
    #pragma unroll
    for (int r = 0; r < 4; ++r) srow[mi][r] = 0.f;

  bf16x8 af[2][2][2];                      // [parity][kh][mi] A-frag double buffer

  // ---- prologue: A(0) frags + W tiles 0..5 of first stripe ----
  lda(af[0], Ab, 0, lr, lg);
  {
    const long c0 = (long)nblk * 64;
    #pragma unroll
    for (int pk = 0; pk < 6; ++pk) stage_w(W16g, wldsb, pk, pk, c0, wave, lane);
  }

  for (int s = nblk; s < NST; s += NBN) {
    const long col0 = (long)s * 64;
    const long ncol0 = (long)(s + NBN) * 64;
    const bool has_next = (s + NBN) < NST;
    // opaque A base: stops LICM from hoisting all 8 phases' A-loads into a
    // 128-reg stripe-invariant array (the r8-r11 spill trap)
    asm volatile("" : "+v"(Ab));

    PHASE(0, 8); PHASE(1, 8); PHASE(2, 6); PHASE(3, 4);
    PHASE(4, 4); PHASE(5, 4); PHASE(6, 4); PHASE(7, 4);

    // ---- register-only epilogue: fixed max = S, srow += exp2(fma(c,K,-K)) ----
    // (zero-padded W cols contribute exp2(-92.3) ~ 2e-28 -> no masking needed)
    #pragma unroll
    for (int mi = 0; mi < 2; ++mi)
      #pragma unroll
      for (int ni = 0; ni < 4; ++ni)
        #pragma unroll
        for (int r = 0; r < 4; ++r) {
          float c = fminf(1.f, fmaxf(-1.f, acc[mi][ni][r]));   // med3
          srow[mi][r] += exp2f(fmaf(c, S_LOG2E, -S_LOG2E));
          acc[mi][ni][r] = 0.f;
        }
  }

  // ---- final per-row reduce over the 16 lr-lanes, write partials ----
  #pragma unroll
  for (int mi = 0; mi < 2; ++mi)
    #pragma unroll
    for (int r = 0; r < 4; ++r) {
      float v = srow[mi][r];
      v += __shfl_xor(v, 1); v += __shfl_xor(v, 2);
      v += __shfl_xor(v, 4); v += __shfl_xor(v, 8);
      if (lr == 0)
        part_s[(size_t)nblk * NROWS + mblk * 128 + wave * 32 + mi * 16 + lg * 4 + r] = v;
    }
}

// ---------------- kernel 3: precise f32 target logit + merge partials ----------------
__global__ void finalize_kernel(const float* __restrict__ X, const int* __restrict__ labels,
                                const float* __restrict__ Wg, const float* __restrict__ xnorm,
                                const float* __restrict__ part_s, float* __restrict__ rowloss) {
  const int row = blockIdx.x;
  const int lane = threadIdx.x;   // 64
  const int lbl = labels[row];
  const float4* xp = (const float4*)(X + (size_t)row * DIM);
  const float4* wp = (const float4*)(Wg + (size_t)lbl * DIM);
  float dot = 0.f, wss = 0.f;
  #pragma unroll
  for (int i = 0; i < 2; ++i) {
    float4 xv = xp[lane + 64 * i];
    float4 wv = wp[lane + 64 * i];
    dot += xv.x*wv.x + xv.y*wv.y + xv.z*wv.z + xv.w*wv.w;
    wss += wv.x*wv.x + wv.y*wv.y + wv.z*wv.z + wv.w*wv.w;
  }
  float psum = 0.f;
  #pragma unroll
  for (int i = 0; i < NBN / 64; ++i)
    psum += part_s[(size_t)(lane + 64 * i) * NROWS + row];
  #pragma unroll
  for (int m = 1; m < 64; m <<= 1) {
    dot += __shfl_xor(dot, m); wss += __shfl_xor(wss, m); psum += __shfl_xor(psum, m);
  }
  if (lane == 0) {
    float c = dot / (fmaxf(xnorm[row], 1e-12f) * fmaxf(sqrtf(wss), 1e-12f));
    c = fminf(1.f, fmaxf(-1.f, c));
    const float cm = 0.99500416527802576610f;   // cos(0.1)
    const float sn = 0.09983341664682815230f;   // sin(0.1)
    float unmod = SCALE_S * c;                  // term the GEMM summed at the label column
    float modv  = SCALE_S * (c * cm - sqrtf(fmaxf(0.f, 1.f - c * c)) * sn); // S*cos(theta+m)
    float stot = psum - __expf(unmod - SCALE_S) + __expf(modv - SCALE_S);
    stot = fmaxf(stot, 1e-37f);
    rowloss[row] = (logf(stot) + SCALE_S) - modv;   // logsumexp - target logit
  }
}

// ---------------- kernel 4: mean over rows ----------------
__global__ void reduce_kernel(const float* __restrict__ rowloss, float* __restrict__ out) {
  const int tid = threadIdx.x;   // 256
  float s = 0.f;
  #pragma unroll
  for (int i = 0; i < 4; ++i) s += rowloss[tid + i * 256];
  #pragma unroll
  for (int m = 1; m < 64; m <<= 1) s += __shfl_xor(s, m);
  __shared__ float wsum[4];
  if ((tid & 63) == 0) wsum[tid >> 6] = s;
  __syncthreads();
  if (tid == 0) out[0] = (wsum[0] + wsum[1] + wsum[2] + wsum[3]) * (1.0f / NROWS);
}

extern "C" void kernel_launch(void* const* d_in, const int* in_sizes, int n_in,
                              void* d_out, int out_size, void* d_ws, size_t ws_size,
                              hipStream_t stream) {
  const float* X      = (const float*)d_in[0];
  const int*   labels = (const int*)d_in[1];
  const float* Wg     = (const float*)d_in[2];
  float* out = (float*)d_out;
  char* ws = (char*)d_ws;
  // ws layout (bytes):
  //   A16    @ 0          1,048,576
  //   W16    @ 1,048,576  102,432,768   (100032 x 512 x 2B, rows >= NCLS zeroed)
  //   part_s @ 103,481,344   786,432    (NBN x 1024 x 4B)
  //   xnorm  @ 104,267,776     4,096
  //   rowloss@ 104,271,872     4,096
  unsigned short* A16 = (unsigned short*)ws;
  unsigned short* W16 = (unsigned short*)(ws + 1048576);
  float* part_s  = (float*)(ws + 103481344);
  float* xnorm   = (float*)(ws + 104267776);
  float* rowloss = (float*)(ws + 104271872);

  prep_a<<<NROWS, 64, 0, stream>>>(X, A16, xnorm);
  prep_w<<<NCLS_PAD / 4, 256, 0, stream>>>(Wg, W16);
  gemm_lse4<<<NBN * 8, 256, 0, stream>>>(A16, W16, part_s);
  finalize_kernel<<<NROWS, 64, 0, stream>>>(X, labels, Wg, xnorm, part_s, rowloss);
  reduce_kernel<<<1, 256, 0, stream>>>(rowloss, out);
}